// Round 5
// baseline (2862.927 us; speedup 1.0000x reference)
//
#include <hip/hip_runtime.h>

#define N_USERS 50000
#define N_ENT   150000
#define N_NODES 200000
#define NE      2000000
#define BATCH   8192
#define NB 782          // ceil(N_NODES / 256)

// ===========================================================================
// CSR build: histogram -> exclusive scan -> atomic-cursor fill (+ crow).
// After fill, rs[r] == row_end; row_start = rs[r] - deg[r].
// ===========================================================================
__global__ __launch_bounds__(256) void hist_kernel(const int* __restrict__ rows,
                                                   int* __restrict__ deg) {
    int e = blockIdx.x * 256 + threadIdx.x;
    if (e < NE) atomicAdd(&deg[rows[e]], 1);
}

__global__ __launch_bounds__(256) void scan1(const int* __restrict__ deg,
                                             int* __restrict__ rs,
                                             int* __restrict__ blk) {
    __shared__ int buf[256];
    int i = blockIdx.x * 256 + threadIdx.x;
    int v = (i < N_NODES) ? deg[i] : 0;
    buf[threadIdx.x] = v;
    __syncthreads();
    for (int off = 1; off < 256; off <<= 1) {
        int x = (threadIdx.x >= off) ? buf[threadIdx.x - off] : 0;
        __syncthreads();
        buf[threadIdx.x] += x;
        __syncthreads();
    }
    if (i < N_NODES) rs[i] = buf[threadIdx.x] - v;       // exclusive
    if (threadIdx.x == 255) blk[blockIdx.x] = buf[255];
}

__global__ __launch_bounds__(1024) void scan2(int* __restrict__ blk) {
    __shared__ int buf[1024];
    int t = threadIdx.x;
    int v = (t < NB) ? blk[t] : 0;
    buf[t] = v;
    __syncthreads();
    for (int off = 1; off < 1024; off <<= 1) {
        int x = (t >= off) ? buf[t - off] : 0;
        __syncthreads();
        buf[t] += x;
        __syncthreads();
    }
    if (t < NB) blk[t] = buf[t] - v;
}

__global__ __launch_bounds__(256) void scan3(int* __restrict__ rs,
                                             const int* __restrict__ blk) {
    int i = blockIdx.x * 256 + threadIdx.x;
    if (i < N_NODES) rs[i] += blk[blockIdx.x];
}

__global__ __launch_bounds__(256) void fill_kernel(const int* __restrict__ rows,
                                                   const int* __restrict__ cols,
                                                   const float* __restrict__ vals,
                                                   int* __restrict__ rs,
                                                   int* __restrict__ ccol,
                                                   float* __restrict__ cval,
                                                   int* __restrict__ crow) {
    int e = blockIdx.x * 256 + threadIdx.x;
    if (e >= NE) return;
    int r = rows[e];
    int pos = atomicAdd(&rs[r], 1);
    ccol[pos] = cols[e];
    cval[pos] = vals[e];
    crow[pos] = r;
}

// ===========================================================================
// Edge-parallel gather: block owns rows [r0, r0+64) (edges CSR-contiguous).
// DIN/4 lanes per edge, float4 gather (256B/edge coalesced), LDS f32 atomic
// accumulate into side tile (pad +1 breaks stride-4 bank lattice), then
// coalesced writeout. Rows fully block-owned -> NO global atomics.
// 4 edges unrolled per thread-group -> 4 float4 loads in flight each.
// ===========================================================================
template <int DIN, int L0>
__global__ __launch_bounds__(256) void gather_kernel(
        const int* __restrict__ rs, const int* __restrict__ deg,
        const int* __restrict__ ccol, const float* __restrict__ cval,
        const int* __restrict__ crow,
        const float* __restrict__ ue, const float* __restrict__ ee,
        const float* __restrict__ xin, float* __restrict__ side_g) {
    constexpr int LPE = DIN / 4;       // lanes per edge (16 or 8)
    constexpr int GROUPS = 256 / LPE;  // edges per block round (16 or 32)
    constexpr int PAD = DIN + 1;
    __shared__ float ss[64 * PAD];
    const int tid = threadIdx.x;
    for (int i = tid; i < 64 * PAD; i += 256) ss[i] = 0.f;
    const int r0     = blockIdx.x * 64;
    const int estart = rs[r0] - deg[r0];
    const int eend   = rs[r0 + 63];
    const int group  = tid / LPE;
    const int sub    = tid % LPE;
    __syncthreads();

    for (int eb = estart; eb < eend; eb += GROUPS * 4) {
#pragma unroll
        for (int u = 0; u < 4; u++) {
            int e = eb + u * GROUPS + group;
            if (e < eend) {
                int   col = ccol[e];
                float v   = cval[e];
                int   lr  = crow[e] - r0;
                float4 x;
                if (L0) {
                    const float* base = (col < N_USERS)
                        ? (ue + (size_t)col * 64)
                        : (ee + (size_t)(col - N_USERS) * 64);
                    x = ((const float4*)base)[sub];
                } else {
                    x = ((const float4*)(xin + (size_t)col * DIN))[sub];
                }
                float* d = &ss[lr * PAD + sub * 4];
                __hip_atomic_fetch_add(d + 0, v * x.x, __ATOMIC_RELAXED, __HIP_MEMORY_SCOPE_WORKGROUP);
                __hip_atomic_fetch_add(d + 1, v * x.y, __ATOMIC_RELAXED, __HIP_MEMORY_SCOPE_WORKGROUP);
                __hip_atomic_fetch_add(d + 2, v * x.z, __ATOMIC_RELAXED, __HIP_MEMORY_SCOPE_WORKGROUP);
                __hip_atomic_fetch_add(d + 3, v * x.w, __ATOMIC_RELAXED, __HIP_MEMORY_SCOPE_WORKGROUP);
            }
        }
    }
    __syncthreads();
    for (int i = tid; i < 64 * DIN; i += 256) {
        int r = i / DIN, d = i % DIN;
        side_g[(size_t)(r0 + r) * DIN + d] = ss[r * PAD + d];
    }
}

// ===========================================================================
// Transform: R = 64/DOUT rows per wave; block = 1024 (16 waves) so weight-LDS
// is amortized to full occupancy. Shuffle-both-registers-then-select (the
// verified r2 pattern). Writes UNNORMALIZED xout (stride DOUT) + row norm;
// normalization is folded into the scoring kernel (divide by norm product).
// ===========================================================================
template <int DIN, int DOUT, int L0>
__global__ __launch_bounds__(1024) void transform_kernel(
        const float* __restrict__ ue, const float* __restrict__ ee,
        const float* __restrict__ xin,   // stride DIN (ignored if L0)
        const float* __restrict__ side,  // stride DIN
        const float* __restrict__ Wg, const float* __restrict__ bg,
        const float* __restrict__ Wb, const float* __restrict__ bb,
        float* __restrict__ xout,        // stride DOUT, unnormalized
        float* __restrict__ norm_out) {
    __shared__ float sWg[DIN * DOUT];
    __shared__ float sWb[DIN * DOUT];
    __shared__ float sbg[DOUT];
    __shared__ float sbb[DOUT];
    for (int i = threadIdx.x; i < DIN * DOUT; i += 1024) {
        sWg[i] = Wg[i];
        sWb[i] = Wb[i];
    }
    if (threadIdx.x < DOUT) {
        sbg[threadIdx.x] = bg[threadIdx.x];
        sbb[threadIdx.x] = bb[threadIdx.x];
    }
    __syncthreads();

    constexpr int R     = 64 / DOUT;         // rows per wave
    constexpr int NSLOT = R * DIN;           // 64 or 128 (always full)
    constexpr int REGS  = (NSLOT + 63) / 64; // 1 or 2

    const int lane  = threadIdx.x & 63;
    const int wave  = threadIdx.x >> 6;
    const int sub   = lane / DOUT;           // row within wave
    const int j     = lane % DOUT;           // output column
    const int wrow0 = blockIdx.x * (16 * R) + wave * R;

    float hreg[REGS], preg[REGS];
#pragma unroll
    for (int t = 0; t < REGS; t++) {
        int slot = lane + t * 64;            // slot < NSLOT always (grids exact)
        int r = slot / DIN, k = slot % DIN;
        int row = wrow0 + r;
        float e;
        if (L0) {
            e = (row < N_USERS) ? ue[(size_t)row * 64 + k]
                                : ee[(size_t)(row - N_USERS) * 64 + k];
        } else {
            e = xin[(size_t)row * DIN + k];
        }
        float s = side[(size_t)row * DIN + k];
        hreg[t] = e + s;
        preg[t] = e * s;
    }

    float ag = sbg[j];
    float ab = sbb[j];
#pragma unroll
    for (int k = 0; k < DIN; k++) {
        const int slot = sub * DIN + k;
        const int src  = slot & 63;
        float hk, pk;
        if (REGS > 1) {
            float h0 = __shfl(hreg[0], src);
            float p0 = __shfl(preg[0], src);
            float h1 = __shfl(hreg[REGS - 1], src);
            float p1 = __shfl(preg[REGS - 1], src);
            int rsel = slot >> 6;
            hk = rsel ? h1 : h0;
            pk = rsel ? p1 : p0;
        } else {
            hk = __shfl(hreg[0], src);
            pk = __shfl(preg[0], src);
        }
        ag = fmaf(hk, sWg[k * DOUT + j], ag);
        ab = fmaf(pk, sWb[k * DOUT + j], ab);
    }
    ag = ag > 0.f ? ag : 0.01f * ag;   // leaky_relu slope 0.01
    ab = ab > 0.f ? ab : 0.01f * ab;
    float nv = ag + ab;

    float ss = nv * nv;                // l2 norm over the DOUT lanes of this row
#pragma unroll
    for (int off = DOUT / 2; off > 0; off >>= 1) ss += __shfl_xor(ss, off);
    float nrm = fmaxf(sqrtf(ss), 1e-12f);

    const int row = wrow0 + sub;
    xout[(size_t)row * DOUT + j] = nv;
    if (j == 0) norm_out[row] = nrm;
}

// ===========================================================================
// Scoring: one wave per batch element. Sections: [0,64) raw ue/ee,
// [64,128) e1/(n0 n0), [128,160) e2/(n1 n1), [160,176) e3/(n2 n2).
// ===========================================================================
__global__ __launch_bounds__(256) void score_kernel(
        const int* __restrict__ users, const int* __restrict__ pos,
        const int* __restrict__ neg,
        const float* __restrict__ ue, const float* __restrict__ ee,
        const float* __restrict__ e1, const float* __restrict__ n0,
        const float* __restrict__ e2, const float* __restrict__ n1,
        const float* __restrict__ e3, const float* __restrict__ n2,
        float* __restrict__ out) {
    int gid  = blockIdx.x * 256 + threadIdx.x;
    int idx  = gid >> 6;
    int lane = gid & 63;
    if (idx >= BATCH) return;
    int u  = users[idx];              // < N_USERS
    int pe = pos[idx];                // entity index
    int ne = neg[idx];
    int pn = N_USERS + pe;            // global node ids
    int nn = N_USERS + ne;

    float s1p = 1.0f / (n0[u] * n0[pn]);
    float s1n = 1.0f / (n0[u] * n0[nn]);
    float s2p = 1.0f / (n1[u] * n1[pn]);
    float s2n = 1.0f / (n1[u] * n1[nn]);
    float s3p = 1.0f / (n2[u] * n2[pn]);
    float s3n = 1.0f / (n2[u] * n2[nn]);

    float ap = 0.f, an = 0.f;
    // section 0: raw embeddings
    {
        float xu = ue[(size_t)u * 64 + lane];
        ap += xu * ee[(size_t)pe * 64 + lane];
        an += xu * ee[(size_t)ne * 64 + lane];
    }
    // section 1: layer-0 output (64 dims)
    {
        float xu = e1[(size_t)u * 64 + lane];
        ap += xu * e1[(size_t)pn * 64 + lane] * s1p;
        an += xu * e1[(size_t)nn * 64 + lane] * s1n;
    }
    // sections 2+3: layer-1 (32 dims) and layer-2 (16 dims)
    if (lane < 32) {
        float xu = e2[(size_t)u * 32 + lane];
        ap += xu * e2[(size_t)pn * 32 + lane] * s2p;
        an += xu * e2[(size_t)nn * 32 + lane] * s2n;
    } else if (lane < 48) {
        int d = lane - 32;
        float xu = e3[(size_t)u * 16 + d];
        ap += xu * e3[(size_t)pn * 16 + d] * s3p;
        an += xu * e3[(size_t)nn * 16 + d] * s3n;
    }
#pragma unroll
    for (int off = 32; off > 0; off >>= 1) {
        ap += __shfl_xor(ap, off);
        an += __shfl_xor(an, off);
    }
    if (lane == 0) {
        out[2 * idx + 0] = ap;
        out[2 * idx + 1] = an;
    }
}

// ===========================================================================
extern "C" void kernel_launch(void* const* d_in, const int* in_sizes, int n_in,
                              void* d_out, int out_size, void* d_ws, size_t ws_size,
                              hipStream_t stream) {
    const int*   users = (const int*)d_in[0];
    const int*   pos   = (const int*)d_in[1];
    const int*   neg   = (const int*)d_in[2];
    const int*   rows  = (const int*)d_in[3];
    const int*   cols  = (const int*)d_in[4];
    const float* vals  = (const float*)d_in[5];
    const float* ue    = (const float*)d_in[6];
    const float* ee    = (const float*)d_in[7];
    const float* Wg0 = (const float*)d_in[8],  *bg0 = (const float*)d_in[9];
    const float* Wb0 = (const float*)d_in[10], *bb0 = (const float*)d_in[11];
    const float* Wg1 = (const float*)d_in[12], *bg1 = (const float*)d_in[13];
    const float* Wb1 = (const float*)d_in[14], *bb1 = (const float*)d_in[15];
    const float* Wg2 = (const float*)d_in[16], *bg2 = (const float*)d_in[17];
    const float* Wb2 = (const float*)d_in[18], *bb2 = (const float*)d_in[19];

    // workspace (~169 MB; <=192 MB proven available in round 2)
    float* e1   = (float*)d_ws;                      // N x 64 (unnormalized)
    float* e2   = e1   + (size_t)N_NODES * 64;       // N x 32
    float* e3   = e2   + (size_t)N_NODES * 32;       // N x 16
    float* n0   = e3   + (size_t)N_NODES * 16;       // N
    float* n1   = n0   + N_NODES;                    // N
    float* n2   = n1   + N_NODES;                    // N
    float* side = n2   + N_NODES;                    // N x 64 scratch
    float* cval = side + (size_t)N_NODES * 64;       // E
    int*   ccol = (int*)(cval + NE);                 // E
    int*   crow = ccol + NE;                         // E
    int*   deg  = crow + NE;                         // N
    int*   rs   = deg  + N_NODES;                    // N
    int*   blk  = rs   + N_NODES;                    // 1024

    // ---- CSR build (once, reused by all 3 layers) ----
    hipMemsetAsync(deg, 0, N_NODES * sizeof(int), stream);
    hist_kernel<<<(NE + 255) / 256, 256, 0, stream>>>(rows, deg);
    scan1<<<NB, 256, 0, stream>>>(deg, rs, blk);
    scan2<<<1, 1024, 0, stream>>>(blk);
    scan3<<<NB, 256, 0, stream>>>(rs, blk);
    fill_kernel<<<(NE + 255) / 256, 256, 0, stream>>>(rows, cols, vals, rs, ccol, cval, crow);

    // ---- layer 0 ----
    gather_kernel<64, 1><<<3125, 256, 0, stream>>>(rs, deg, ccol, cval, crow,
                                                   ue, ee, nullptr, side);
    transform_kernel<64, 64, 1><<<12500, 1024, 0, stream>>>(ue, ee, nullptr, side,
                                                            Wg0, bg0, Wb0, bb0, e1, n0);
    // ---- layer 1 ----
    gather_kernel<64, 0><<<3125, 256, 0, stream>>>(rs, deg, ccol, cval, crow,
                                                   ue, ee, e1, side);
    transform_kernel<64, 32, 0><<<6250, 1024, 0, stream>>>(ue, ee, e1, side,
                                                           Wg1, bg1, Wb1, bb1, e2, n1);
    // ---- layer 2 ----
    gather_kernel<32, 0><<<3125, 256, 0, stream>>>(rs, deg, ccol, cval, crow,
                                                   ue, ee, e2, side);
    transform_kernel<32, 16, 0><<<3125, 1024, 0, stream>>>(ue, ee, e2, side,
                                                           Wg2, bg2, Wb2, bb2, e3, n2);

    // ---- scoring ----
    score_kernel<<<(BATCH * 64) / 256, 256, 0, stream>>>(users, pos, neg, ue, ee,
                                                         e1, n0, e2, n1, e3, n2,
                                                         (float*)d_out);
}